// Round 6
// baseline (5065.228 us; speedup 1.0000x reference)
//
#include <hip/hip_runtime.h>
#include <math.h>

#define L_DIM 3072
#define B_DIM 64
#define H_DIM 256
#define HP2 260         // h-tile stride (floats): 16B-aligned rows; phase-2 reads conflict-free (rows s*8+ty)
#define PP 49           // p-tile stride: odd -> epilogue reads spread across banks
#define TWO_PI_F 6.28318530717958647692f
#define EPS_F 1e-6f

__device__ __forceinline__ float mod2pi(float x){
    float q = floorf(x * (1.0f/TWO_PI_F));
    return fmaf(-TWO_PI_F, q, x);
}

// tanh(x) = 1 - 2/(e^{2x}+1); ~1e-7 abs err, exact saturation.
__device__ __forceinline__ float fast_tanh(float x){
    float t = __expf(2.0f*x);
    return 1.0f - __fdividef(2.0f, t + 1.0f);
}

__global__ __launch_bounds__(256) void init_kernel(const float* __restrict__ zin, float* __restrict__ out){
    int i = blockIdx.x*256 + threadIdx.x;
    if (i < B_DIM*L_DIM) out[i] = zin[i];
    if (i < B_DIM) out[B_DIM*L_DIM + i] = 0.0f;   // zero ldj accumulators
}

// One coupling round. 64 sites/block, 256 threads (4 waves), grid 1024, 2 blocks/CU.
// Phase 2 tiled 8 sites x 8 cols per thread: 256 FMA per (8 LDS + 8 global) insts —
// halves LDS-pipe pressure vs 16x4 tiling (the r4 structural stall).
__global__ __launch_bounds__(256, 2) void round_kernel(
    float* __restrict__ z, float* __restrict__ ldj,
    const float* __restrict__ W1, const float* __restrict__ b1,
    const float* __restrict__ W2, const float* __restrict__ b2,
    const float* __restrict__ W3, const float* __restrict__ b3,
    int off)
{
    __shared__ float h_lds[64*HP2];       // 66560 B: h1 tile, then reused for h2
    __shared__ float p_lds[64*PP];        // 12544 B: params
    __shared__ float c1_l[64], c2_l[64], u_l[64], zr_l[64];

    const int tid = threadIdx.x;
    const int bid = blockIdx.x;
    const int b  = bid >> 4;              // batch (16 blocks per batch)
    const int j0 = (bid & 15) << 6;       // first site of block
    float* zb = z + b*L_DIM;

    // -------- Phase 0: stencil / context --------
    if (tid < 64){
        int idx = 3*(j0 + tid) + off;
        int im2 = idx-2; if (im2 < 0) im2 += L_DIM;
        int im1 = idx-1; if (im1 < 0) im1 += L_DIM;
        int ip1 = idx+1; if (ip1 >= L_DIM) ip1 -= L_DIM;
        int ip2 = idx+2; if (ip2 >= L_DIM) ip2 -= L_DIM;
        float zi  = zb[idx];
        float zm1 = zb[im1];
        float zm2 = zb[im2];
        float zp1 = zb[ip1];
        float zp2 = zb[ip2];
        c1_l[tid] = mod2pi(zm1 - zm2);    // V[idx-1]
        c2_l[tid] = mod2pi(zp2 - zp1);    // V[idx+2]
        float V   = mod2pi(zi - zm1);     // V[idx]
        float u = V * (1.0f/TWO_PI_F);
        u_l[tid] = fminf(fmaxf(u, EPS_F), 1.0f-EPS_F);
        zr_l[tid] = zm1;
    }
    __syncthreads();

    // -------- Phase 1: h1[m][k] = tanh(c1*W1[0,k] + c2*W1[1,k] + b1[k]), k = tid --------
    {
        float w0 = W1[tid];
        float w1 = W1[H_DIM + tid];
        float bb = b1[tid];
        #pragma unroll 8
        for (int m=0; m<64; m++){
            float pre = fmaf(c1_l[m], w0, fmaf(c2_l[m], w1, bb));
            h_lds[m*HP2 + tid] = fast_tanh(pre);
        }
    }
    __syncthreads();

    // -------- Phase 2: h1(64x256) @ W2(256x256); wave w owns cols [64w, 64w+64) --------
    const int wv   = tid >> 6;            // wave 0..3 -> col slice
    const int lane = tid & 63;
    const int ty = lane >> 3;             // 0..7 : site group (sites s*8+ty)
    const int tx = lane & 7;              // 0..7 : col group (8 cols each)
    const int c4 = wv*16 + tx*2;          // first float4 col index within W2 row

    float acc[8][8];
    #pragma unroll
    for (int s=0; s<8; s++)
        #pragma unroll
        for (int c=0; c<8; c++) acc[s][c] = 0.f;

    const float4* __restrict__ W2v = (const float4*)W2;
    float4 wq[4][2];
    #pragma unroll
    for (int j=0; j<4; j++){
        wq[j][0] = W2v[j*64 + c4];
        wq[j][1] = W2v[j*64 + c4 + 1];
    }

    for (int k=0; k<H_DIM; k+=4){
        // current k-quad activations (8 sites, rows s*8+ty -> all 32 banks, conflict-free)
        float4 av[8];
        #pragma unroll
        for (int s=0; s<8; s++)
            av[s] = *(const float4*)&h_lds[(s*8+ty)*HP2 + k];
        // prefetch next k-quad weights into registers (hide L1/L2 latency under FMAs)
        int kn = k + 4; if (kn >= H_DIM) kn = 0;
        float4 wqn[4][2];
        #pragma unroll
        for (int j=0; j<4; j++){
            wqn[j][0] = W2v[(kn+j)*64 + c4];
            wqn[j][1] = W2v[(kn+j)*64 + c4 + 1];
        }
        #pragma unroll
        for (int s=0; s<8; s++){
            float a4[4] = {av[s].x, av[s].y, av[s].z, av[s].w};
            #pragma unroll
            for (int j=0; j<4; j++){
                float a = a4[j];
                acc[s][0] = fmaf(a, wq[j][0].x, acc[s][0]);
                acc[s][1] = fmaf(a, wq[j][0].y, acc[s][1]);
                acc[s][2] = fmaf(a, wq[j][0].z, acc[s][2]);
                acc[s][3] = fmaf(a, wq[j][0].w, acc[s][3]);
                acc[s][4] = fmaf(a, wq[j][1].x, acc[s][4]);
                acc[s][5] = fmaf(a, wq[j][1].y, acc[s][5]);
                acc[s][6] = fmaf(a, wq[j][1].z, acc[s][6]);
                acc[s][7] = fmaf(a, wq[j][1].w, acc[s][7]);
            }
        }
        #pragma unroll
        for (int j=0; j<4; j++){
            wq[j][0] = wqn[j][0];
            wq[j][1] = wqn[j][1];
        }
    }
    __syncthreads();      // all h1 reads done

    // -------- Phase 3: h2 = tanh(acc + b2) back into LDS (2x float4 stores per site) --------
    {
        const int n0 = wv*64 + tx*8;
        float4 bb0 = *(const float4*)&b2[n0];
        float4 bb1 = *(const float4*)&b2[n0+4];
        #pragma unroll
        for (int s=0; s<8; s++){
            int m = s*8 + ty;
            float4 o0, o1;
            o0.x = fast_tanh(acc[s][0] + bb0.x);
            o0.y = fast_tanh(acc[s][1] + bb0.y);
            o0.z = fast_tanh(acc[s][2] + bb0.z);
            o0.w = fast_tanh(acc[s][3] + bb0.w);
            o1.x = fast_tanh(acc[s][4] + bb1.x);
            o1.y = fast_tanh(acc[s][5] + bb1.y);
            o1.z = fast_tanh(acc[s][6] + bb1.z);
            o1.w = fast_tanh(acc[s][7] + bb1.w);
            *(float4*)&h_lds[m*HP2 + n0]     = o0;
            *(float4*)&h_lds[m*HP2 + n0 + 4] = o1;
        }
    }
    __syncthreads();

    // -------- Phase 4: params(64x48) = h2 @ W3 + b3 --------
    // site = lane (per-lane), output-block = wave index (uniform) -> W3/b3 loads are
    // wave-uniform scalar (s_load) broadcasts: no vector-memory traffic.
    {
        const int m4 = lane;
        const int ol = __builtin_amdgcn_readfirstlane(wv);   // 0..3, 12 params each
        float acc3[12];
        #pragma unroll
        for (int r=0; r<12; r++) acc3[r] = 0.f;
        const float4* __restrict__ W3v = (const float4*)W3;  // [k][12 float4]
        for (int k=0; k<H_DIM; k+=4){
            float4 hv = *(const float4*)&h_lds[m4*HP2 + k];
            float hw[4] = {hv.x, hv.y, hv.z, hv.w};
            #pragma unroll
            for (int j=0; j<4; j++){
                float h = hw[j];
                float4 q0 = W3v[(k+j)*12 + ol*3 + 0];
                float4 q1 = W3v[(k+j)*12 + ol*3 + 1];
                float4 q2 = W3v[(k+j)*12 + ol*3 + 2];
                acc3[0] = fmaf(h, q0.x, acc3[0]);  acc3[1] = fmaf(h, q0.y, acc3[1]);
                acc3[2] = fmaf(h, q0.z, acc3[2]);  acc3[3] = fmaf(h, q0.w, acc3[3]);
                acc3[4] = fmaf(h, q1.x, acc3[4]);  acc3[5] = fmaf(h, q1.y, acc3[5]);
                acc3[6] = fmaf(h, q1.z, acc3[6]);  acc3[7] = fmaf(h, q1.w, acc3[7]);
                acc3[8] = fmaf(h, q2.x, acc3[8]);  acc3[9] = fmaf(h, q2.y, acc3[9]);
                acc3[10]= fmaf(h, q2.z, acc3[10]); acc3[11]= fmaf(h, q2.w, acc3[11]);
            }
        }
        #pragma unroll
        for (int r=0; r<12; r++)
            p_lds[m4*PP + ol*12 + r] = acc3[r] + b3[ol*12 + r];
    }
    __syncthreads();

    // -------- Phase 5: epilogue, one thread per site (wave 0) --------
    float ll = 0.0f;
    if (tid < 64){
        const float* p = p_lds + tid*PP;  // [0..15] log_scale, [16..31] shift, [32..47] wlogit
        float mx = p[32];
        #pragma unroll
        for (int i=1; i<16; i++) mx = fmaxf(mx, p[32+i]);
        float w[16]; float se = 0.0f;
        #pragma unroll
        for (int i=0; i<16; i++){ w[i] = __expf(p[32+i]-mx); se += w[i]; }
        float inv = __fdividef(0.84f, se);   // (1 - K*MIN_W)/sum

        float u = u_l[tid];
        float a  = u*u;
        float om = 1.0f - u;
        float b_ = om*om;
        float apb = a + b_;
        float s = __fdividef(a, apb);
        float ds_du = __fdividef(2.0f*u*om, apb*apb);
        s = fminf(fmaxf(s, EPS_F), 1.0f-EPS_F);
        float logit_s = __logf(s) - log1pf(-s);

        float y = 0.0f, dd = 0.0f;
        #pragma unroll
        for (int i=0; i<16; i++){
            float alpha = __expf(p[i]);
            float wgt = fmaf(w[i], inv, 0.01f);
            float targ = alpha * (logit_s + p[16+i]);
            float g = __fdividef(1.0f, 1.0f + __expf(-targ));
            y  = fmaf(wgt, g, y);
            dd = fmaf(wgt*alpha, g*(1.0f-g), dd);
        }
        float dy_du = __fdividef(dd, s*(1.0f-s)) * ds_du;
        ll = __logf(dy_du);

        int idx = 3*(j0 + tid) + off;
        zb[idx] = mod2pi(fmaf(TWO_PI_F, y, zr_l[tid]));
    }
    // wave-0 butterfly reduction of ll, one atomic per block
    if (tid < 64){
        #pragma unroll
        for (int o=32; o>0; o>>=1) ll += __shfl_down(ll, o, 64);
        if (tid == 0) atomicAdd(&ldj[b], ll);
    }
}

extern "C" void kernel_launch(void* const* d_in, const int* in_sizes, int n_in,
                              void* d_out, int out_size, void* d_ws, size_t ws_size,
                              hipStream_t stream) {
    const float* z_in = (const float*)d_in[0];
    const float* W1 = (const float*)d_in[1];
    const float* b1 = (const float*)d_in[2];
    const float* W2 = (const float*)d_in[3];
    const float* b2 = (const float*)d_in[4];
    const float* W3 = (const float*)d_in[5];
    const float* b3 = (const float*)d_in[6];
    float* out = (float*)d_out;
    float* zbuf = out;                    // z worked in-place in d_out
    float* ldj  = out + B_DIM*L_DIM;

    init_kernel<<<(B_DIM*L_DIM + 255)/256, 256, 0, stream>>>(z_in, out);

    for (int t=0; t<12; t++){
        int r = t % 3;
        int off = (r==0) ? 0 : ((r==1) ? 2 : 1);
        round_kernel<<<1024, 256, 0, stream>>>(
            zbuf, ldj,
            W1 + t*2*H_DIM, b1 + t*H_DIM,
            W2 + t*H_DIM*H_DIM, b2 + t*H_DIM,
            W3 + t*H_DIM*48, b3 + t*48,
            off);
    }
}

// Round 7
// 2592.940 us; speedup vs baseline: 1.9535x; 1.9535x over previous
//
#include <hip/hip_runtime.h>
#include <math.h>

#define L_DIM 3072
#define B_DIM 64
#define H_DIM 256
#define HP2 260         // h-tile stride (floats): 1040 B/row, 16B-aligned; row-per-lane reads 2-way = free
#define PP 49           // p-tile stride: odd -> epilogue reads spread across banks
#define TWO_PI_F 6.28318530717958647692f
#define EPS_F 1e-6f

__device__ __forceinline__ float mod2pi(float x){
    float q = floorf(x * (1.0f/TWO_PI_F));
    return fmaf(-TWO_PI_F, q, x);
}

// tanh(x) = 1 - 2/(e^{2x}+1); ~1e-7 abs err, exact saturation.
__device__ __forceinline__ float fast_tanh(float x){
    float t = __expf(2.0f*x);
    return 1.0f - __fdividef(2.0f, t + 1.0f);
}

__global__ __launch_bounds__(256) void init_kernel(const float* __restrict__ zin, float* __restrict__ out){
    int i = blockIdx.x*256 + threadIdx.x;
    if (i < B_DIM*L_DIM) out[i] = zin[i];
    if (i < B_DIM) out[B_DIM*L_DIM + i] = 0.0f;   // zero ldj accumulators
}

// One coupling round. 64 sites/block (= lane id), 256 threads (4 waves), grid 1024.
// Phase 2: lane = site, wave = 64-col slice. W2 is lane-uniform -> s_load broadcast
// (zero vector-mem traffic); h1 read = 1 ds_read_b128 per k-quad per wave.
__global__ __launch_bounds__(256, 2) void round_kernel(
    float* __restrict__ z, float* __restrict__ ldj,
    const float* __restrict__ W1, const float* __restrict__ b1,
    const float* __restrict__ W2, const float* __restrict__ b2,
    const float* __restrict__ W3, const float* __restrict__ b3,
    int off)
{
    __shared__ float h_lds[64*HP2];       // 66560 B: h1 tile, then reused for h2
    __shared__ float p_lds[64*PP];        // 12544 B: params
    __shared__ float c1_l[64], c2_l[64], u_l[64], zr_l[64];

    const int tid  = threadIdx.x;
    const int lane = tid & 63;                                  // site id
    const int wv_u = __builtin_amdgcn_readfirstlane(tid >> 6);  // uniform wave id 0..3
    const int bid = blockIdx.x;
    const int b  = bid >> 4;              // batch (16 blocks per batch)
    const int j0 = (bid & 15) << 6;       // first site of block
    float* zb = z + b*L_DIM;

    // -------- Phase 0: stencil / context --------
    if (tid < 64){
        int idx = 3*(j0 + tid) + off;
        int im2 = idx-2; if (im2 < 0) im2 += L_DIM;
        int im1 = idx-1; if (im1 < 0) im1 += L_DIM;
        int ip1 = idx+1; if (ip1 >= L_DIM) ip1 -= L_DIM;
        int ip2 = idx+2; if (ip2 >= L_DIM) ip2 -= L_DIM;
        float zi  = zb[idx];
        float zm1 = zb[im1];
        float zm2 = zb[im2];
        float zp1 = zb[ip1];
        float zp2 = zb[ip2];
        c1_l[tid] = mod2pi(zm1 - zm2);    // V[idx-1]
        c2_l[tid] = mod2pi(zp2 - zp1);    // V[idx+2]
        float V   = mod2pi(zi - zm1);     // V[idx]
        float u = V * (1.0f/TWO_PI_F);
        u_l[tid] = fminf(fmaxf(u, EPS_F), 1.0f-EPS_F);
        zr_l[tid] = zm1;
    }
    __syncthreads();

    // -------- Phase 1: h1[m][k] = tanh(c1*W1[0,k] + c2*W1[1,k] + b1[k]), k = tid --------
    {
        float w0 = W1[tid];
        float w1 = W1[H_DIM + tid];
        float bb = b1[tid];
        #pragma unroll 8
        for (int m=0; m<64; m++){
            float pre = fmaf(c1_l[m], w0, fmaf(c2_l[m], w1, bb));
            h_lds[m*HP2 + tid] = fast_tanh(pre);
        }
    }
    __syncthreads();

    // -------- Phase 2: acc[site=lane][64 cols of this wave] = h1[lane][:] @ W2[:, slice] --------
    float acc[64];
    #pragma unroll
    for (int c=0; c<64; c++) acc[c] = 0.f;

    {
        const float* __restrict__ W2w = W2 + wv_u*64;     // uniform col-slice base
        float4 h4 = *(const float4*)&h_lds[lane*HP2];     // k=0 quad
        for (int k=0; k<H_DIM; k+=4){
            // 1-deep LDS prefetch of next quad (wraps to 0 on last iter; harmless)
            float4 h4n = *(const float4*)&h_lds[lane*HP2 + ((k+4) & (H_DIM-1))];
            float hk[4] = {h4.x, h4.y, h4.z, h4.w};
            #pragma unroll
            for (int j=0; j<4; j++){
                const float* wrow = W2w + (k+j)*H_DIM;    // uniform address -> s_load
                #pragma unroll
                for (int q=0; q<16; q++){
                    float4 wq = *(const float4*)(wrow + q*4);
                    acc[q*4+0] = fmaf(hk[j], wq.x, acc[q*4+0]);
                    acc[q*4+1] = fmaf(hk[j], wq.y, acc[q*4+1]);
                    acc[q*4+2] = fmaf(hk[j], wq.z, acc[q*4+2]);
                    acc[q*4+3] = fmaf(hk[j], wq.w, acc[q*4+3]);
                }
            }
            h4 = h4n;
        }
    }
    __syncthreads();      // all h1 reads done

    // -------- Phase 3: h2 = tanh(acc + b2) back into own LDS row (col slice) --------
    {
        const int n0 = wv_u*64;
        #pragma unroll
        for (int q=0; q<16; q++){
            float4 bb = *(const float4*)&b2[n0 + q*4];    // uniform -> s_load
            float4 o;
            o.x = fast_tanh(acc[q*4+0] + bb.x);
            o.y = fast_tanh(acc[q*4+1] + bb.y);
            o.z = fast_tanh(acc[q*4+2] + bb.z);
            o.w = fast_tanh(acc[q*4+3] + bb.w);
            *(float4*)&h_lds[lane*HP2 + n0 + q*4] = o;
        }
    }
    __syncthreads();

    // -------- Phase 4: params(64x48) = h2 @ W3 + b3 --------
    // site = lane, output-block = wave (uniform) -> W3/b3 via s_load broadcasts.
    {
        float acc3[12];
        #pragma unroll
        for (int r=0; r<12; r++) acc3[r] = 0.f;
        const float4* __restrict__ W3v = (const float4*)W3;  // [k][12 float4]
        for (int k=0; k<H_DIM; k+=4){
            float4 hv = *(const float4*)&h_lds[lane*HP2 + k];
            float hw[4] = {hv.x, hv.y, hv.z, hv.w};
            #pragma unroll
            for (int j=0; j<4; j++){
                float h = hw[j];
                float4 q0 = W3v[(k+j)*12 + wv_u*3 + 0];
                float4 q1 = W3v[(k+j)*12 + wv_u*3 + 1];
                float4 q2 = W3v[(k+j)*12 + wv_u*3 + 2];
                acc3[0] = fmaf(h, q0.x, acc3[0]);  acc3[1] = fmaf(h, q0.y, acc3[1]);
                acc3[2] = fmaf(h, q0.z, acc3[2]);  acc3[3] = fmaf(h, q0.w, acc3[3]);
                acc3[4] = fmaf(h, q1.x, acc3[4]);  acc3[5] = fmaf(h, q1.y, acc3[5]);
                acc3[6] = fmaf(h, q1.z, acc3[6]);  acc3[7] = fmaf(h, q1.w, acc3[7]);
                acc3[8] = fmaf(h, q2.x, acc3[8]);  acc3[9] = fmaf(h, q2.y, acc3[9]);
                acc3[10]= fmaf(h, q2.z, acc3[10]); acc3[11]= fmaf(h, q2.w, acc3[11]);
            }
        }
        #pragma unroll
        for (int r=0; r<12; r++)
            p_lds[lane*PP + wv_u*12 + r] = acc3[r] + b3[wv_u*12 + r];
    }
    __syncthreads();

    // -------- Phase 5: epilogue, one thread per site (wave 0) --------
    float ll = 0.0f;
    if (tid < 64){
        const float* p = p_lds + tid*PP;  // [0..15] log_scale, [16..31] shift, [32..47] wlogit
        float mx = p[32];
        #pragma unroll
        for (int i=1; i<16; i++) mx = fmaxf(mx, p[32+i]);
        float w[16]; float se = 0.0f;
        #pragma unroll
        for (int i=0; i<16; i++){ w[i] = __expf(p[32+i]-mx); se += w[i]; }
        float inv = __fdividef(0.84f, se);   // (1 - K*MIN_W)/sum

        float u = u_l[tid];
        float a  = u*u;
        float om = 1.0f - u;
        float b_ = om*om;
        float apb = a + b_;
        float s = __fdividef(a, apb);
        float ds_du = __fdividef(2.0f*u*om, apb*apb);
        s = fminf(fmaxf(s, EPS_F), 1.0f-EPS_F);
        float logit_s = __logf(s) - log1pf(-s);

        float y = 0.0f, dd = 0.0f;
        #pragma unroll
        for (int i=0; i<16; i++){
            float alpha = __expf(p[i]);
            float wgt = fmaf(w[i], inv, 0.01f);
            float targ = alpha * (logit_s + p[16+i]);
            float g = __fdividef(1.0f, 1.0f + __expf(-targ));
            y  = fmaf(wgt, g, y);
            dd = fmaf(wgt*alpha, g*(1.0f-g), dd);
        }
        float dy_du = __fdividef(dd, s*(1.0f-s)) * ds_du;
        ll = __logf(dy_du);

        int idx = 3*(j0 + tid) + off;
        zb[idx] = mod2pi(fmaf(TWO_PI_F, y, zr_l[tid]));
    }
    // wave-0 butterfly reduction of ll, one atomic per block
    if (tid < 64){
        #pragma unroll
        for (int o=32; o>0; o>>=1) ll += __shfl_down(ll, o, 64);
        if (tid == 0) atomicAdd(&ldj[b], ll);
    }
}

extern "C" void kernel_launch(void* const* d_in, const int* in_sizes, int n_in,
                              void* d_out, int out_size, void* d_ws, size_t ws_size,
                              hipStream_t stream) {
    const float* z_in = (const float*)d_in[0];
    const float* W1 = (const float*)d_in[1];
    const float* b1 = (const float*)d_in[2];
    const float* W2 = (const float*)d_in[3];
    const float* b2 = (const float*)d_in[4];
    const float* W3 = (const float*)d_in[5];
    const float* b3 = (const float*)d_in[6];
    float* out = (float*)d_out;
    float* zbuf = out;                    // z worked in-place in d_out
    float* ldj  = out + B_DIM*L_DIM;

    init_kernel<<<(B_DIM*L_DIM + 255)/256, 256, 0, stream>>>(z_in, out);

    for (int t=0; t<12; t++){
        int r = t % 3;
        int off = (r==0) ? 0 : ((r==1) ? 2 : 1);
        round_kernel<<<1024, 256, 0, stream>>>(
            zbuf, ldj,
            W1 + t*2*H_DIM, b1 + t*H_DIM,
            W2 + t*H_DIM*H_DIM, b2 + t*H_DIM,
            W3 + t*H_DIM*48, b3 + t*48,
            off);
    }
}